// Round 1
// baseline (941.620 us; speedup 1.0000x reference)
//
#include <hip/hip_runtime.h>

typedef __attribute__((ext_vector_type(8))) short s8v;
typedef __attribute__((ext_vector_type(4))) short s4v;
typedef __attribute__((ext_vector_type(4))) float f4v;

#define DEVI static __device__ __forceinline__

DEVI unsigned short f2bf(float f) {
  unsigned u = __float_as_uint(f);
  u = (u + 0x7FFFu + ((u >> 16) & 1u)) >> 16;
  return (unsigned short)u;
}
DEVI float bf2f(unsigned short b) { return __uint_as_float(((unsigned)b) << 16); }

#define MFMA(a, b, c) __builtin_amdgcn_mfma_f32_16x16x32_bf16((a), (b), (c), 0, 0, 0)

// ---------------------------------------------------------------- transpose W (fp32 [k][n] -> bf16 [n][k])
__global__ __launch_bounds__(256) void k_wt(const float* __restrict__ W,
                                            unsigned short* __restrict__ WT) {
  __shared__ unsigned short T[64][72];
  const int n0 = blockIdx.x * 64, k0 = blockIdx.y * 64;
  const int t = threadIdx.x;
  {
    const int r = t >> 2, c0 = (t & 3) * 16;
    const float* src = W + (k0 + r) * 1024 + n0 + c0;
#pragma unroll
    for (int jj = 0; jj < 4; ++jj) {
      f4v v = *(const f4v*)(src + jj * 4);
#pragma unroll
      for (int e = 0; e < 4; ++e) T[r][c0 + jj * 4 + e] = f2bf(v[e]);
    }
  }
  __syncthreads();
  {
    const int n = t >> 2, c0 = (t & 3) * 16;
    unsigned short* dst = WT + (n0 + n) * 1024 + k0 + c0;
    s8v o0, o1;
#pragma unroll
    for (int j = 0; j < 8; ++j) {
      o0[j] = (short)T[c0 + j][n];
      o1[j] = (short)T[c0 + 8 + j][n];
    }
    *(s8v*)dst = o0;
    *(s8v*)(dst + 8) = o1;
  }
}

// ---------------------------------------------------------------- big GEMM: C[16384x1024] = A @ W + bias
// A: fp32 (converted on the fly) or bf16.  Bt = W^T bf16 [n][k].  Out: bf16 or fp32.
template <bool AF32, bool OF32>
__global__ __launch_bounds__(256, 2) void k_gemm(const void* __restrict__ Ap,
                                                 const unsigned short* __restrict__ Bt,
                                                 const float* __restrict__ bias,
                                                 void* __restrict__ Outp) {
  __shared__ unsigned short As[128 * 40];
  __shared__ unsigned short Bs[128 * 40];
  const int n0 = blockIdx.x * 128, m0 = blockIdx.y * 128;
  const int t = threadIdx.x, lane = t & 63, w = t >> 6;
  const int c16 = lane & 15, g = lane >> 4;
  const int wr = (w >> 1) * 64, wc = (w & 1) * 64;
  const int srow = t >> 1, skc = (t & 1) * 16;
  f4v acc[4][4] = {};
  for (int kt = 0; kt < 32; ++kt) {
    const int kb = kt * 32;
    s8v a0, a1, b0, b1;
    if (AF32) {
      const float* a = (const float*)Ap + (m0 + srow) * 1024 + kb + skc;
#pragma unroll
      for (int j = 0; j < 2; ++j) {
        f4v v0 = *(const f4v*)(a + j * 8);
        f4v v1 = *(const f4v*)(a + j * 8 + 4);
#pragma unroll
        for (int e = 0; e < 4; ++e) {
          if (j == 0) { a0[e] = (short)f2bf(v0[e]); a0[4 + e] = (short)f2bf(v1[e]); }
          else        { a1[e] = (short)f2bf(v0[e]); a1[4 + e] = (short)f2bf(v1[e]); }
        }
      }
    } else {
      const unsigned short* a = (const unsigned short*)Ap + (m0 + srow) * 1024 + kb + skc;
      a0 = *(const s8v*)a;
      a1 = *(const s8v*)(a + 8);
    }
    {
      const unsigned short* bsrc = Bt + (n0 + srow) * 1024 + kb + skc;
      b0 = *(const s8v*)bsrc;
      b1 = *(const s8v*)(bsrc + 8);
    }
    __syncthreads();  // previous iteration's ds_reads drained
    *(s8v*)&As[srow * 40 + skc] = a0;
    *(s8v*)&As[srow * 40 + skc + 8] = a1;
    *(s8v*)&Bs[srow * 40 + skc] = b0;
    *(s8v*)&Bs[srow * 40 + skc + 8] = b1;
    __syncthreads();
    s8v afr[4], bfr[4];
#pragma unroll
    for (int mi = 0; mi < 4; ++mi) afr[mi] = *(s8v*)&As[(wr + mi * 16 + c16) * 40 + 8 * g];
#pragma unroll
    for (int ni = 0; ni < 4; ++ni) bfr[ni] = *(s8v*)&Bs[(wc + ni * 16 + c16) * 40 + 8 * g];
#pragma unroll
    for (int mi = 0; mi < 4; ++mi)
#pragma unroll
      for (int ni = 0; ni < 4; ++ni) acc[mi][ni] = MFMA(afr[mi], bfr[ni], acc[mi][ni]);
  }
  float bvv[4];
#pragma unroll
  for (int ni = 0; ni < 4; ++ni) bvv[ni] = bias[n0 + wc + ni * 16 + c16];
#pragma unroll
  for (int mi = 0; mi < 4; ++mi)
#pragma unroll
    for (int r = 0; r < 4; ++r) {
      const int row = m0 + wr + mi * 16 + 4 * g + r;
#pragma unroll
      for (int ni = 0; ni < 4; ++ni) {
        const int col = n0 + wc + ni * 16 + c16;
        const float v = acc[mi][ni][r] + bvv[ni];
        if (OF32) ((float*)Outp)[row * 1024 + col] = v;
        else ((unsigned short*)Outp)[row * 1024 + col] = f2bf(v);
      }
    }
}

// ---------------------------------------------------------------- landmark pooling (mean of 32 rows)
__global__ __launch_bounds__(256) void k_land(const unsigned short* __restrict__ qb,
                                              const unsigned short* __restrict__ kb,
                                              float* __restrict__ Qlf, float* __restrict__ Klf,
                                              unsigned short* __restrict__ Qlb,
                                              unsigned short* __restrict__ Klb) {
  const int bh = blockIdx.y, which = blockIdx.z;
  const unsigned short* src = which ? kb : qb;
  float* dF = which ? Klf : Qlf;
  unsigned short* dB = which ? Klb : Qlb;
  const int m = blockIdx.x * 4 + (threadIdx.x >> 6);
  const int d = threadIdx.x & 63;
  const int b = bh >> 4, h = bh & 15;
  const unsigned short* p = src + ((b * 4096 + m * 32) * 16 + h) * 64 + d;
  float s = 0.f;
#pragma unroll 8
  for (int i = 0; i < 32; ++i) s += bf2f(p[i * 1024]);
  s *= (1.0f / 32.0f);
  dF[(bh * 128 + m) * 64 + d] = s;
  dB[(bh * 128 + m) * 64 + d] = f2bf(s);
}

// ---------------------------------------------------------------- kernel_2 softmax (fp32) + NS init
__global__ __launch_bounds__(256) void k_k2(const float* __restrict__ Qlf,
                                            const float* __restrict__ Klf,
                                            float* __restrict__ K2, float* __restrict__ V0,
                                            float* __restrict__ V0T) {
  __shared__ float LS[8192];
  __shared__ float aux[132];
  unsigned short* P2 = (unsigned short*)LS;
  const int bh = blockIdx.x;
  const int t = threadIdx.x;
  const float* Kb = Klf + bh * 8192;
  for (int i = t; i < 8192; i += 256) LS[i] = Kb[i];
  __syncthreads();
  const int m = t >> 1, ch = t & 1;
  const float* Qr = Qlf + bh * 8192 + m * 64;
  float dv[64];
#pragma unroll
  for (int n = 0; n < 64; ++n) {
    const float* kr = &LS[(ch * 64 + n) * 64];
    float s = 0.f;
    for (int j = 0; j < 64; ++j) s = fmaf(Qr[j], kr[j], s);
    dv[n] = s;
  }
  float mx = -1e30f;
#pragma unroll
  for (int n = 0; n < 64; ++n) mx = fmaxf(mx, dv[n]);
  mx = fmaxf(mx, __shfl_xor(mx, 1));
  float sm = 0.f;
#pragma unroll
  for (int n = 0; n < 64; ++n) {
    dv[n] = __expf(dv[n] - mx);
    sm += dv[n];
  }
  sm += __shfl_xor(sm, 1);
  const float is = 1.0f / sm;
  float* K2r = K2 + bh * 16384 + m * 128 + ch * 64;
#pragma unroll
  for (int n = 0; n < 64; ++n) {
    dv[n] *= is;
    K2r[n] = dv[n];
  }
  __syncthreads();  // done reading LS (Klf)
#pragma unroll
  for (int n = 0; n < 64; ++n) P2[m * 128 + ch * 64 + n] = f2bf(dv[n]);
  __syncthreads();
  if (t < 128) {
    float s = 0.f;
    for (int i = 0; i < 128; ++i) s += bf2f(P2[i * 128 + t]);
    aux[t] = s;
  }
  __syncthreads();
  if (t < 64) {
    float v = fmaxf(aux[t], aux[t + 64]);
#pragma unroll
    for (int off = 1; off < 64; off <<= 1) v = fmaxf(v, __shfl_xor(v, off));
    if (t == 0) aux[128] = 1.0f / v;
  }
  __syncthreads();
  const float scale = aux[128];
  float* V0b = V0 + bh * 16384;
  float* V0Tb = V0T + bh * 16384;
  for (int idx = t; idx < 16384; idx += 256) {
    const int mm = idx >> 7, nn = idx & 127;
    const float v = bf2f(P2[idx]) * scale;
    V0Tb[idx] = v;          // V0^T = scale*K2
    V0b[nn * 128 + mm] = v; // V0   = scale*K2^T
  }
}

// ---------------------------------------------------------------- Newton-Schulz batched matmul (split-bf16, ~fp32)
// C = A @ B with Bt = B^T supplied.  EPI 0: store C and Ct=alpha*I-C^T
//                                    EPI 1: store only Ct=alpha*I-C^T
//                                    EPI 2: C*=0.25, store C and Ct=C^T
template <int EPI>
__global__ __launch_bounds__(256) void k_nsmm(const float* __restrict__ A,
                                              const float* __restrict__ Bt,
                                              float* __restrict__ C, float* __restrict__ Ct,
                                              const float alpha) {
  __shared__ unsigned short Ah[64 * 40], Al[64 * 40], Bh[64 * 40], Bl[64 * 40];
  const int bh = blockIdx.y;
  const int m0 = (blockIdx.x >> 1) * 64, n0 = (blockIdx.x & 1) * 64;
  const float* Ab = A + bh * 16384;
  const float* Bb = Bt + bh * 16384;
  const int t = threadIdx.x, lane = t & 63, w = t >> 6;
  const int c16 = lane & 15, g = lane >> 4;
  const int wr = (w >> 1) * 32, wc = (w & 1) * 32;
  const int srow = t >> 2, sc = (t & 3) * 8;
  f4v acc[2][2] = {};
  for (int kc = 0; kc < 4; ++kc) {
    const float* pa = Ab + (m0 + srow) * 128 + kc * 32 + sc;
    const float* pb = Bb + (n0 + srow) * 128 + kc * 32 + sc;
    s8v ah, al, bhv, blv;
#pragma unroll
    for (int j = 0; j < 8; ++j) {
      float va = pa[j];
      unsigned short hh = f2bf(va);
      ah[j] = (short)hh;
      al[j] = (short)f2bf(va - bf2f(hh));
      float vx = pb[j];
      hh = f2bf(vx);
      bhv[j] = (short)hh;
      blv[j] = (short)f2bf(vx - bf2f(hh));
    }
    __syncthreads();
    *(s8v*)&Ah[srow * 40 + sc] = ah;
    *(s8v*)&Al[srow * 40 + sc] = al;
    *(s8v*)&Bh[srow * 40 + sc] = bhv;
    *(s8v*)&Bl[srow * 40 + sc] = blv;
    __syncthreads();
    s8v fah[2], fal[2], fbh[2], fbl[2];
#pragma unroll
    for (int i = 0; i < 2; ++i) {
      fah[i] = *(s8v*)&Ah[(wr + i * 16 + c16) * 40 + 8 * g];
      fal[i] = *(s8v*)&Al[(wr + i * 16 + c16) * 40 + 8 * g];
      fbh[i] = *(s8v*)&Bh[(wc + i * 16 + c16) * 40 + 8 * g];
      fbl[i] = *(s8v*)&Bl[(wc + i * 16 + c16) * 40 + 8 * g];
    }
#pragma unroll
    for (int mi = 0; mi < 2; ++mi)
#pragma unroll
      for (int ni = 0; ni < 2; ++ni) {
        acc[mi][ni] = MFMA(fah[mi], fbh[ni], acc[mi][ni]);
        acc[mi][ni] = MFMA(fah[mi], fbl[ni], acc[mi][ni]);
        acc[mi][ni] = MFMA(fal[mi], fbh[ni], acc[mi][ni]);
      }
  }
#pragma unroll
  for (int mi = 0; mi < 2; ++mi)
#pragma unroll
    for (int ni = 0; ni < 2; ++ni) {
      const int rowb = m0 + wr + mi * 16 + 4 * g;
      const int col = n0 + wc + ni * 16 + c16;
      f4v v = acc[mi][ni];
      if (EPI == 2) v *= 0.25f;
      if (EPI != 1) {
#pragma unroll
        for (int r = 0; r < 4; ++r) C[bh * 16384 + (rowb + r) * 128 + col] = v[r];
      }
      f4v tv;
#pragma unroll
      for (int r = 0; r < 4; ++r) {
        if (EPI == 2) tv[r] = v[r];
        else tv[r] = ((rowb + r) == col ? alpha : 0.f) - v[r];
      }
      *(f4v*)&Ct[bh * 16384 + col * 128 + rowb] = tv;
    }
}

// ---------------------------------------------------------------- v^T materialization [bh][80][L] (row 64 = ones)
__global__ __launch_bounds__(256) void k_vt(const unsigned short* __restrict__ vb,
                                            unsigned short* __restrict__ vT) {
  __shared__ unsigned short T[64][72];
  const int lt = blockIdx.x, bh = blockIdx.y;
  const int b = bh >> 4, h = bh & 15;
  const int t = threadIdx.x;
  {
    const int r = t >> 2, c0 = (t & 3) * 16;
    const unsigned short* src = vb + ((b * 4096 + lt * 64 + r) * 16 + h) * 64 + c0;
    *(s8v*)&T[r][c0] = *(const s8v*)src;
    *(s8v*)&T[r][c0 + 8] = *(const s8v*)(src + 8);
  }
  __syncthreads();
  {
    const int d = t >> 2, c0 = (t & 3) * 16;
    unsigned short* dst = vT + (bh * 80 + d) * 4096 + lt * 64 + c0;
    s8v o0, o1;
#pragma unroll
    for (int j = 0; j < 8; ++j) {
      o0[j] = (short)T[c0 + j][d];
      o1[j] = (short)T[c0 + 8 + j][d];
    }
    *(s8v*)dst = o0;
    *(s8v*)(dst + 8) = o1;
  }
}

__global__ void k_ones(unsigned short* __restrict__ vT) {
  const int bh = blockIdx.y;
  const int i = blockIdx.x * 256 + threadIdx.x;
  vT[(bh * 80 + 64) * 4096 + i] = 0x3F80;  // bf16 1.0
}

// ---------------------------------------------------------------- kernel_3 @ v, flash over L (exp without shift: logits ~N(0,0.56))
__global__ __launch_bounds__(256) void k_flash(const unsigned short* __restrict__ Qlb,
                                               const unsigned short* __restrict__ kb,
                                               const unsigned short* __restrict__ vT,
                                               float* __restrict__ Opart,
                                               float* __restrict__ dpart) {
  __shared__ unsigned short P3[128 * 72];
  const int chunk = blockIdx.x, bh = blockIdx.y;
  const int b = bh >> 4, h = bh & 15;
  const int t = threadIdx.x, lane = t & 63, w = t >> 6;
  const int c16 = lane & 15, g = lane >> 4;
  s8v aq[8][2];
#pragma unroll
  for (int mi = 0; mi < 8; ++mi)
#pragma unroll
    for (int ks = 0; ks < 2; ++ks)
      aq[mi][ks] = *(const s8v*)&Qlb[(bh * 128 + mi * 16 + c16) * 64 + ks * 32 + 8 * g];
  f4v accO[2][5] = {};
  for (int s = 0; s < 16; ++s) {
    const int l0 = chunk * 1024 + s * 64;
    const int lcol = l0 + 16 * w + c16;
    const unsigned short* kr = &kb[((b * 4096 + lcol) * 16 + h) * 64];
    s8v bk0 = *(const s8v*)&kr[8 * g];
    s8v bk1 = *(const s8v*)&kr[32 + 8 * g];
    f4v p[8];
#pragma unroll
    for (int mi = 0; mi < 8; ++mi) {
      f4v a = {};
      a = MFMA(aq[mi][0], bk0, a);
      a = MFMA(aq[mi][1], bk1, a);
      p[mi] = a;
    }
    __syncthreads();  // previous PV reads done
#pragma unroll
    for (int mi = 0; mi < 8; ++mi)
#pragma unroll
      for (int r = 0; r < 4; ++r)
        P3[(mi * 16 + 4 * g + r) * 72 + 16 * w + c16] = f2bf(__expf(p[mi][r]));
    __syncthreads();
#pragma unroll
    for (int ks = 0; ks < 2; ++ks) {
      s8v ap0 = *(s8v*)&P3[(32 * w + c16) * 72 + ks * 32 + 8 * g];
      s8v ap1 = *(s8v*)&P3[(32 * w + 16 + c16) * 72 + ks * 32 + 8 * g];
#pragma unroll
      for (int ni = 0; ni < 5; ++ni) {
        s8v bv = *(const s8v*)&vT[(bh * 80 + ni * 16 + c16) * 4096 + l0 + ks * 32 + 8 * g];
        accO[0][ni] = MFMA(ap0, bv, accO[0][ni]);
        accO[1][ni] = MFMA(ap1, bv, accO[1][ni]);
      }
    }
  }
  const int obase = (bh * 4 + chunk) * 128 * 64;
#pragma unroll
  for (int mi2 = 0; mi2 < 2; ++mi2)
#pragma unroll
    for (int ni = 0; ni < 4; ++ni)
#pragma unroll
      for (int r = 0; r < 4; ++r)
        Opart[obase + (32 * w + mi2 * 16 + 4 * g + r) * 64 + ni * 16 + c16] = accO[mi2][ni][r];
  if (c16 == 0) {
#pragma unroll
    for (int mi2 = 0; mi2 < 2; ++mi2)
#pragma unroll
      for (int r = 0; r < 4; ++r)
        dpart[(bh * 4 + chunk) * 128 + 32 * w + mi2 * 16 + 4 * g + r] = accO[mi2][4][r];
  }
}

// ---------------------------------------------------------------- combine partials -> k3v^T hi/lo bf16 [bh][d][m]
__global__ __launch_bounds__(256) void k_comb(const float* __restrict__ Opart,
                                              const float* __restrict__ dpart,
                                              unsigned short* __restrict__ k3h,
                                              unsigned short* __restrict__ k3l) {
  const int bh = blockIdx.x;
  const int t = threadIdx.x;
  for (int idx = t; idx < 8192; idx += 256) {
    const int m = idx >> 6, d = idx & 63;
    float s = 0.f, den = 0.f;
#pragma unroll
    for (int c = 0; c < 4; ++c) {
      s += Opart[((bh * 4 + c) * 128 + m) * 64 + d];
      den += dpart[(bh * 4 + c) * 128 + m];
    }
    const float v = s / den;
    const unsigned short hh = f2bf(v);
    k3h[(bh * 64 + d) * 128 + m] = hh;
    k3l[(bh * 64 + d) * 128 + m] = f2bf(v - bf2f(hh));
  }
}

// ---------------------------------------------------------------- Z = inv @ k3v  (split x split, store Z^T hi/lo)
__global__ __launch_bounds__(256) void k_zmm(const float* __restrict__ inv,
                                             const unsigned short* __restrict__ k3h,
                                             const unsigned short* __restrict__ k3l,
                                             unsigned short* __restrict__ ZTh,
                                             unsigned short* __restrict__ ZTl) {
  __shared__ unsigned short Ah[128 * 40], Al[128 * 40];
  const int bh = blockIdx.x;
  const int t = threadIdx.x, lane = t & 63, w = t >> 6;
  const int c16 = lane & 15, g = lane >> 4;
  const int wr = w * 32;
  const int srow = t >> 1, sc = (t & 1) * 16;
  f4v acc[2][4] = {};
  for (int kc = 0; kc < 4; ++kc) {
    const float* pa = inv + bh * 16384 + srow * 128 + kc * 32 + sc;
    s8v h0, lo0, h1, lo1;
#pragma unroll
    for (int j = 0; j < 8; ++j) {
      float va = pa[j];
      unsigned short hh = f2bf(va);
      h0[j] = (short)hh;
      lo0[j] = (short)f2bf(va - bf2f(hh));
      va = pa[8 + j];
      hh = f2bf(va);
      h1[j] = (short)hh;
      lo1[j] = (short)f2bf(va - bf2f(hh));
    }
    __syncthreads();
    *(s8v*)&Ah[srow * 40 + sc] = h0;
    *(s8v*)&Ah[srow * 40 + sc + 8] = h1;
    *(s8v*)&Al[srow * 40 + sc] = lo0;
    *(s8v*)&Al[srow * 40 + sc + 8] = lo1;
    __syncthreads();
    s8v fah[2], fal[2];
#pragma unroll
    for (int mi = 0; mi < 2; ++mi) {
      fah[mi] = *(s8v*)&Ah[(wr + mi * 16 + c16) * 40 + 8 * g];
      fal[mi] = *(s8v*)&Al[(wr + mi * 16 + c16) * 40 + 8 * g];
    }
#pragma unroll
    for (int ni = 0; ni < 4; ++ni) {
      s8v fbh = *(const s8v*)&k3h[(bh * 64 + ni * 16 + c16) * 128 + kc * 32 + 8 * g];
      s8v fbl = *(const s8v*)&k3l[(bh * 64 + ni * 16 + c16) * 128 + kc * 32 + 8 * g];
#pragma unroll
      for (int mi = 0; mi < 2; ++mi) {
        acc[mi][ni] = MFMA(fah[mi], fbh, acc[mi][ni]);
        acc[mi][ni] = MFMA(fah[mi], fbl, acc[mi][ni]);
        acc[mi][ni] = MFMA(fal[mi], fbh, acc[mi][ni]);
      }
    }
  }
#pragma unroll
  for (int mi = 0; mi < 2; ++mi)
#pragma unroll
    for (int ni = 0; ni < 4; ++ni) {
      const int rowb = wr + mi * 16 + 4 * g;
      const int col = ni * 16 + c16;
      s4v hv, lv;
#pragma unroll
      for (int r = 0; r < 4; ++r) {
        const float z = acc[mi][ni][r];
        const unsigned short hh = f2bf(z);
        hv[r] = (short)hh;
        lv[r] = (short)f2bf(z - bf2f(hh));
      }
      *(s4v*)&ZTh[(bh * 64 + col) * 128 + rowb] = hv;
      *(s4v*)&ZTl[(bh * 64 + col) * 128 + rowb] = lv;
    }
}

// ---------------------------------------------------------------- kernel_1: softmax(q @ K_l^T) -> P1 bf16
__global__ __launch_bounds__(256) void k_p1(const unsigned short* __restrict__ qb,
                                            const unsigned short* __restrict__ Klb,
                                            unsigned short* __restrict__ P1) {
  const int lt = blockIdx.x, bh = blockIdx.y;
  const int b = bh >> 4, h = bh & 15;
  const int t = threadIdx.x, lane = t & 63, w = t >> 6;
  const int c16 = lane & 15, g = lane >> 4;
  const int lrow = lt * 64 + 16 * w + c16;
  const unsigned short* qr = &qb[((b * 4096 + lrow) * 16 + h) * 64];
  s8v aq0 = *(const s8v*)&qr[8 * g];
  s8v aq1 = *(const s8v*)&qr[32 + 8 * g];
  f4v acc[8];
#pragma unroll
  for (int ni = 0; ni < 8; ++ni) {
    f4v a = {};
    s8v b0 = *(const s8v*)&Klb[(bh * 128 + ni * 16 + c16) * 64 + 8 * g];
    s8v b1 = *(const s8v*)&Klb[(bh * 128 + ni * 16 + c16) * 64 + 32 + 8 * g];
    a = MFMA(aq0, b0, a);
    a = MFMA(aq1, b1, a);
    acc[ni] = a;
  }
#pragma unroll
  for (int r = 0; r < 4; ++r) {
    float mx = -1e30f;
#pragma unroll
    for (int ni = 0; ni < 8; ++ni) mx = fmaxf(mx, acc[ni][r]);
#pragma unroll
    for (int off = 1; off < 16; off <<= 1) mx = fmaxf(mx, __shfl_xor(mx, off));
    float sm = 0.f;
#pragma unroll
    for (int ni = 0; ni < 8; ++ni) {
      const float e = __expf(acc[ni][r] - mx);
      acc[ni][r] = e;
      sm += e;
    }
#pragma unroll
    for (int off = 1; off < 16; off <<= 1) sm += __shfl_xor(sm, off);
    const float is = 1.0f / sm;
    const int row = lt * 64 + 16 * w + 4 * g + r;
#pragma unroll
    for (int ni = 0; ni < 8; ++ni)
      P1[(bh * 4096 + row) * 128 + ni * 16 + c16] = f2bf(acc[ni][r] * is);
  }
}

// ---------------------------------------------------------------- X = P1 @ Z  -> bf16 [B,L,1024]
__global__ __launch_bounds__(256) void k_xg(const unsigned short* __restrict__ P1,
                                            const unsigned short* __restrict__ ZTh,
                                            const unsigned short* __restrict__ ZTl,
                                            unsigned short* __restrict__ Xb) {
  const int lt = blockIdx.x, bh = blockIdx.y;
  const int b = bh >> 4, h = bh & 15;
  const int t = threadIdx.x, lane = t & 63, w = t >> 6;
  const int c16 = lane & 15, g = lane >> 4;
  const int wr = w * 32;
  f4v acc[2][4] = {};
  for (int kc = 0; kc < 4; ++kc) {
    s8v ap[2];
#pragma unroll
    for (int mi = 0; mi < 2; ++mi)
      ap[mi] = *(const s8v*)&P1[(bh * 4096 + lt * 128 + wr + mi * 16 + c16) * 128 + kc * 32 + 8 * g];
#pragma unroll
    for (int ni = 0; ni < 4; ++ni) {
      s8v zh = *(const s8v*)&ZTh[(bh * 64 + ni * 16 + c16) * 128 + kc * 32 + 8 * g];
      s8v zl = *(const s8v*)&ZTl[(bh * 64 + ni * 16 + c16) * 128 + kc * 32 + 8 * g];
#pragma unroll
      for (int mi = 0; mi < 2; ++mi) {
        acc[mi][ni] = MFMA(ap[mi], zh, acc[mi][ni]);
        acc[mi][ni] = MFMA(ap[mi], zl, acc[mi][ni]);
      }
    }
  }
#pragma unroll
  for (int mi = 0; mi < 2; ++mi)
#pragma unroll
    for (int ni = 0; ni < 4; ++ni)
#pragma unroll
      for (int r = 0; r < 4; ++r) {
        const int row = lt * 128 + wr + mi * 16 + 4 * g + r;
        Xb[(b * 4096 + row) * 1024 + h * 64 + ni * 16 + c16] = f2bf(acc[mi][ni][r]);
      }
}

// ================================================================ host
extern "C" void kernel_launch(void* const* d_in, const int* in_sizes, int n_in,
                              void* d_out, int out_size, void* d_ws, size_t ws_size,
                              hipStream_t stream) {
  (void)in_sizes; (void)n_in; (void)out_size;
  const float* queries = (const float*)d_in[0];
  const float* keys = (const float*)d_in[1];
  const float* values = (const float*)d_in[2];
  const float* Wq = (const float*)d_in[3];
  const float* bq = (const float*)d_in[4];
  const float* Wk = (const float*)d_in[5];
  const float* bk = (const float*)d_in[6];
  const float* Wv = (const float*)d_in[7];
  const float* bv = (const float*)d_in[8];
  const float* Wo = (const float*)d_in[9];
  const float* bo = (const float*)d_in[10];
  char* ws = (char*)d_ws;
  if (ws_size < (size_t)197263360) return;  // need ~188 MB scratch

  unsigned short* qb = (unsigned short*)(ws + 0);
  unsigned short* kb = (unsigned short*)(ws + 33554432);
  unsigned short* vb = (unsigned short*)(ws + 67108864);
  unsigned short* vT = (unsigned short*)(ws + 100663296);
  unsigned short* WT = (unsigned short*)(ws + 142606336);
  float* Qlf = (float*)(ws + 144703488);
  float* Klf = (float*)(ws + 146800640);
  unsigned short* Qlb = (unsigned short*)(ws + 148897792);
  unsigned short* Klb = (unsigned short*)(ws + 149946368);
  float* K2 = (float*)(ws + 150994944);
  float* Va = (float*)(ws + 155189248);
  float* VaT = (float*)(ws + 159383552);
  float* Vb = (float*)(ws + 163577856);
  float* VbT = (float*)(ws + 167772160);
  float* KV = (float*)(ws + 171966464);
  float* W1 = (float*)(ws + 176160768);
  float* W2 = (float*)(ws + 180355072);
  float* Opart = (float*)(ws + 184549376);
  float* dpart = (float*)(ws + 192937984);
  unsigned short* k3h = (unsigned short*)(ws + 193069056);
  unsigned short* k3l = (unsigned short*)(ws + 194117632);
  unsigned short* ZTh = (unsigned short*)(ws + 195166208);
  unsigned short* ZTl = (unsigned short*)(ws + 196214784);
  unsigned short* Xb = qb;                    // q dead after k_p1
  unsigned short* P1 = (unsigned short*)d_out;  // bf16 P1 scratch in d_out (exact fit)

  // projections q,k,v  ([B,L,H,D] == row-major [BL,1024])
  k_wt<<<dim3(16, 16), 256, 0, stream>>>(Wq, WT);
  k_gemm<true, false><<<dim3(8, 128), 256, 0, stream>>>(queries, WT, bq, qb);
  k_wt<<<dim3(16, 16), 256, 0, stream>>>(Wk, WT);
  k_gemm<true, false><<<dim3(8, 128), 256, 0, stream>>>(keys, WT, bk, kb);
  k_wt<<<dim3(16, 16), 256, 0, stream>>>(Wv, WT);
  k_gemm<true, false><<<dim3(8, 128), 256, 0, stream>>>(values, WT, bv, vb);
  // landmarks
  k_land<<<dim3(32, 64, 2), 256, 0, stream>>>(qb, kb, Qlf, Klf, Qlb, Klb);
  // kernel_2 softmax (fp32) + NS init V0 = K2^T / max colsum
  k_k2<<<dim3(64), 256, 0, stream>>>(Qlf, Klf, K2, Va, VaT);
  // Newton-Schulz, 6 iterations, split-bf16 precision
  float* vin = Va; float* vinT = VaT; float* vout = Vb; float* voutT = VbT;
  for (int it = 0; it < 6; ++it) {
    k_nsmm<0><<<dim3(4, 64), 256, 0, stream>>>(K2, vinT, KV, W1, 7.0f);   // KV, W1T=7I-KV^T
    k_nsmm<1><<<dim3(4, 64), 256, 0, stream>>>(KV, W1, W2, W2, 15.0f);    // W2T=15I-(KV@W1)^T
    k_nsmm<1><<<dim3(4, 64), 256, 0, stream>>>(KV, W2, W1, W1, 13.0f);    // W3T=13I-(KV@W2)^T
    k_nsmm<2><<<dim3(4, 64), 256, 0, stream>>>(vin, W1, vout, voutT, 0.0f);  // V'=0.25 V@W3
    float* tp = vin; vin = vout; vout = tp;
    tp = vinT; vinT = voutT; voutT = tp;
  }
  // kernel_3 @ v, flash over L
  k_vt<<<dim3(64, 64), 256, 0, stream>>>(vb, vT);
  k_ones<<<dim3(16, 64), 256, 0, stream>>>(vT);
  k_flash<<<dim3(4, 64), 256, 0, stream>>>(Qlb, kb, vT, Opart, dpart);
  k_comb<<<dim3(64), 256, 0, stream>>>(Opart, dpart, k3h, k3l);
  // Z = inv @ k3v
  k_zmm<<<dim3(64), 256, 0, stream>>>(vin, k3h, k3l, ZTh, ZTl);
  // kernel_1 softmax -> P1 (in d_out)
  k_p1<<<dim3(64, 64), 256, 0, stream>>>(qb, Klb, P1);
  // X = P1 @ Z -> bf16 [B,L,1024] (over q region)
  k_xg<<<dim3(32, 64), 256, 0, stream>>>(P1, ZTh, ZTl, Xb);
  // out = X @ Wo + bo (fp32 into d_out; P1 fully consumed)
  k_wt<<<dim3(16, 16), 256, 0, stream>>>(Wo, WT);
  k_gemm<false, true><<<dim3(8, 128), 256, 0, stream>>>(Xb, WT, bo, (float*)d_out);
}

// Round 3
// 789.767 us; speedup vs baseline: 1.1923x; 1.1923x over previous
//
#include <hip/hip_runtime.h>

typedef __attribute__((ext_vector_type(8))) short s8v;
typedef __attribute__((ext_vector_type(4))) short s4v;
typedef __attribute__((ext_vector_type(4))) float f4v;

#define DEVI static __device__ __forceinline__

DEVI unsigned short f2bf(float f) {
  unsigned u = __float_as_uint(f);
  u = (u + 0x7FFFu + ((u >> 16) & 1u)) >> 16;
  return (unsigned short)u;
}
DEVI float bf2f(unsigned short b) { return __uint_as_float(((unsigned)b) << 16); }

#define MFMA(a, b, c) __builtin_amdgcn_mfma_f32_16x16x32_bf16((a), (b), (c), 0, 0, 0)

// async global->LDS, 16B per lane; LDS dest is wave-uniform base + lane*16
DEVI void gload16(const void* gsrc, void* ldst) {
  __builtin_amdgcn_global_load_lds(
      (const __attribute__((address_space(1))) unsigned int*)gsrc,
      (__attribute__((address_space(3))) unsigned int*)ldst, 16, 0, 0);
}

// ---------------------------------------------------------------- fp32 -> bf16 convert (one tensor, 16M elems)
__global__ __launch_bounds__(256) void k_cvt(const float* __restrict__ s,
                                             unsigned short* __restrict__ d) {
  const long i = (long)blockIdx.x * 256 + threadIdx.x;
  const float* p = s + i * 8;
  f4v v0 = *(const f4v*)p;
  f4v v1 = *(const f4v*)(p + 4);
  s8v o;
#pragma unroll
  for (int e = 0; e < 4; ++e) {
    o[e] = (short)f2bf(v0[e]);
    o[4 + e] = (short)f2bf(v1[e]);
  }
  *(s8v*)(d + i * 8) = o;
}

// ---------------------------------------------------------------- transpose W (fp32 [k][n] -> bf16 [n][k])
__global__ __launch_bounds__(256) void k_wt(const float* __restrict__ W,
                                            unsigned short* __restrict__ WT) {
  __shared__ unsigned short T[64][72];
  const int n0 = blockIdx.x * 64, k0 = blockIdx.y * 64;
  const int t = threadIdx.x;
  {
    const int r = t >> 2, c0 = (t & 3) * 16;
    const float* src = W + (k0 + r) * 1024 + n0 + c0;
#pragma unroll
    for (int jj = 0; jj < 4; ++jj) {
      f4v v = *(const f4v*)(src + jj * 4);
#pragma unroll
      for (int e = 0; e < 4; ++e) T[r][c0 + jj * 4 + e] = f2bf(v[e]);
    }
  }
  __syncthreads();
  {
    const int n = t >> 2, c0 = (t & 3) * 16;
    unsigned short* dst = WT + (n0 + n) * 1024 + k0 + c0;
    s8v o0, o1;
#pragma unroll
    for (int j = 0; j < 8; ++j) {
      o0[j] = (short)T[c0 + j][n];
      o1[j] = (short)T[c0 + 8 + j][n];
    }
    *(s8v*)dst = o0;
    *(s8v*)(dst + 8) = o1;
  }
}

// ---------------------------------------------------------------- big GEMM (m97 structure):
// C[16384x1024] = A(bf16) @ WT^T + bias.  global_load_lds staging, 128x128 tile, BK=32.
template <bool OF32>
__global__ __launch_bounds__(256) void k_gemm(const unsigned short* __restrict__ A,
                                              const unsigned short* __restrict__ Bt,
                                              const float* __restrict__ bias,
                                              void* __restrict__ Outp) {
  __shared__ unsigned short As[128 * 32];
  __shared__ unsigned short Bs[128 * 32];
  int bid = blockIdx.x;                      // 1024 blocks; 1024%8==0 -> simple bijective XCD swizzle
  bid = ((bid & 7) << 7) + (bid >> 3);
  const int n0 = (bid & 7) * 128;
  const int m0 = (bid >> 3) * 128;
  const int t = threadIdx.x, lane = t & 63, w = t >> 6;
  const int c16 = lane & 15, g = lane >> 4;
  const int wr = (w >> 1) * 64, wc = (w & 1) * 64;
  const unsigned short* Ag = A + (long)(m0 + (t >> 2)) * 1024 + (t & 3) * 8;
  const unsigned short* Bg = Bt + (long)(n0 + (t >> 2)) * 1024 + (t & 3) * 8;
  f4v acc[4][4] = {};
  for (int kt = 0; kt < 32; ++kt) {
    const int kb = kt * 32;
    __syncthreads();  // previous iteration's fragment reads drained
    gload16(Ag + kb, (char*)As + w * 1024);
    gload16(Ag + kb + 64 * 1024, (char*)As + 4096 + w * 1024);
    gload16(Bg + kb, (char*)Bs + w * 1024);
    gload16(Bg + kb + 64 * 1024, (char*)Bs + 4096 + w * 1024);
    __syncthreads();  // compiler drains vmcnt(0) here
    s8v afr[4], bfr[4];
#pragma unroll
    for (int mi = 0; mi < 4; ++mi) afr[mi] = *(s8v*)&As[(wr + mi * 16 + c16) * 32 + 8 * g];
#pragma unroll
    for (int ni = 0; ni < 4; ++ni) bfr[ni] = *(s8v*)&Bs[(wc + ni * 16 + c16) * 32 + 8 * g];
#pragma unroll
    for (int mi = 0; mi < 4; ++mi)
#pragma unroll
      for (int ni = 0; ni < 4; ++ni) acc[mi][ni] = MFMA(afr[mi], bfr[ni], acc[mi][ni]);
  }
  float bvv[4];
#pragma unroll
  for (int ni = 0; ni < 4; ++ni) bvv[ni] = bias[n0 + wc + ni * 16 + c16];
#pragma unroll
  for (int mi = 0; mi < 4; ++mi)
#pragma unroll
    for (int r = 0; r < 4; ++r) {
      const long row = m0 + wr + mi * 16 + 4 * g + r;
#pragma unroll
      for (int ni = 0; ni < 4; ++ni) {
        const int col = n0 + wc + ni * 16 + c16;
        const float v = acc[mi][ni][r] + bvv[ni];
        if (OF32) ((float*)Outp)[row * 1024 + col] = v;
        else ((unsigned short*)Outp)[row * 1024 + col] = f2bf(v);
      }
    }
}

// ---------------------------------------------------------------- landmark pooling (mean of 32 rows)
__global__ __launch_bounds__(256) void k_land(const unsigned short* __restrict__ qb,
                                              const unsigned short* __restrict__ kb,
                                              float* __restrict__ Qlf, float* __restrict__ Klf,
                                              unsigned short* __restrict__ Qlb,
                                              unsigned short* __restrict__ Klb) {
  const int bh = blockIdx.y, which = blockIdx.z;
  const unsigned short* src = which ? kb : qb;
  float* dF = which ? Klf : Qlf;
  unsigned short* dB = which ? Klb : Qlb;
  const int m = blockIdx.x * 4 + (threadIdx.x >> 6);
  const int d = threadIdx.x & 63;
  const int b = bh >> 4, h = bh & 15;
  const unsigned short* p = src + ((b * 4096 + m * 32) * 16 + h) * 64 + d;
  float s = 0.f;
#pragma unroll 8
  for (int i = 0; i < 32; ++i) s += bf2f(p[i * 1024]);
  s *= (1.0f / 32.0f);
  dF[(bh * 128 + m) * 64 + d] = s;
  dB[(bh * 128 + m) * 64 + d] = f2bf(s);
}

// ---------------------------------------------------------------- kernel_2 softmax (fp32) -> K2 split rows,
// V0 = scale*K2^T split rows, scale
__global__ __launch_bounds__(256) void k_k2(const float* __restrict__ Qlf,
                                            const float* __restrict__ Klf,
                                            unsigned short* __restrict__ K2h,
                                            unsigned short* __restrict__ K2l,
                                            unsigned short* __restrict__ Vh,
                                            unsigned short* __restrict__ Vl,
                                            float* __restrict__ scale) {
  __shared__ float S[16384];  // phase1: [0,8192)=Kl rows, [8192,16384)=Ql rows; phase2: probs [128][128]
  __shared__ float cs[128];
  __shared__ float sred;
  const int bh = blockIdx.x;
  const int t = threadIdx.x;
  for (int i = t; i < 8192; i += 256) {
    S[i] = Klf[bh * 8192 + i];
    S[8192 + i] = Qlf[bh * 8192 + i];
  }
  __syncthreads();
  const int m = t >> 1, ch = t & 1;
  const float* Qr = &S[8192 + m * 64];
  float dv[64];
#pragma unroll
  for (int n = 0; n < 64; ++n) {
    const float* kr = &S[(ch * 64 + n) * 64];
    float s = 0.f;
    for (int j = 0; j < 64; ++j) s = fmaf(Qr[j], kr[j], s);
    dv[n] = s;
  }
  float mx = -1e30f;
#pragma unroll
  for (int n = 0; n < 64; ++n) mx = fmaxf(mx, dv[n]);
  mx = fmaxf(mx, __shfl_xor(mx, 1));
  float sm = 0.f;
#pragma unroll
  for (int n = 0; n < 64; ++n) {
    dv[n] = __expf(dv[n] - mx);
    sm += dv[n];
  }
  sm += __shfl_xor(sm, 1);
  const float is = 1.0f / sm;
  __syncthreads();  // all dot-product reads of S done
  float* Srow = &S[m * 128 + ch * 64];
#pragma unroll
  for (int n = 0; n < 64; ++n) Srow[n] = dv[n] * is;
  __syncthreads();
  {  // column sums -> max -> scale
    const int col = t & 127, part = t >> 7;
    float s_ = 0.f;
    for (int r = part * 64; r < part * 64 + 64; ++r) s_ += S[r * 128 + col];
    if (part == 0) cs[col] = s_;
    __syncthreads();
    if (part == 1) cs[col] += s_;
    __syncthreads();
  }
  if (t < 64) {
    float v = fmaxf(cs[t], cs[t + 64]);
#pragma unroll
    for (int off = 1; off < 64; off <<= 1) v = fmaxf(v, __shfl_xor(v, off));
    if (t == 0) {
      sred = 1.0f / v;
      scale[bh] = 1.0f / v;
    }
  }
  __syncthreads();
  const float sc = sred;
  const long base = (long)bh * 16384;
  for (int idx = t; idx < 16384; idx += 256) {
    const int r = idx >> 7, c = idx & 127;
    const float v = S[idx];
    unsigned short hh = f2bf(v);
    K2h[base + idx] = hh;
    K2l[base + idx] = f2bf(v - bf2f(hh));
    const float v0 = sc * S[c * 128 + r];  // V0[r][c] = sc*K2[c][r]
    hh = f2bf(v0);
    Vh[base + idx] = hh;
    Vl[base + idx] = f2bf(v0 - bf2f(hh));
  }
}

// ---------------------------------------------------------------- fused Newton-Schulz (6 iters) + Z = inv @ k3v
// one block per bh. Split-bf16 (hi+lo, 3-term MFMA) throughout, fp32 accumulators.
__global__ __launch_bounds__(256) void k_ns(
    const unsigned short* __restrict__ K2h, const unsigned short* __restrict__ K2l,
    unsigned short* __restrict__ Vh, unsigned short* __restrict__ Vl,
    const unsigned short* __restrict__ k3h, const unsigned short* __restrict__ k3l,
    const float* __restrict__ scale,
    unsigned short* __restrict__ ZTh, unsigned short* __restrict__ ZTl) {
  // 136-short rows (272B = odd*16B): ds_read_b128 at bank floor, 16B aligned
  __shared__ unsigned short BA[2][128][136];
  __shared__ unsigned short BB[2][128][136];
  const int bh = blockIdx.x;
  const int t = threadIdx.x, lane = t & 63, w = t >> 6;
  const int c16 = lane & 15, g = lane >> 4;
  const int wr = (w >> 1) * 64, wc = (w & 1) * 64;
  const int pr = t >> 2, pc = (t & 3) * 8;  // staging map
  unsigned short* SA = &BA[0][0][0];        // stage overlay (16KB) in BA
  unsigned short* SB = &BB[0][0][0];        // stage overlay (16KB) in BB
  const float sc = scale[bh];
  const long kbase = (long)bh * 16384;

#pragma unroll 1
  for (int it = 0; it < 6; ++it) {
    // ---- P1: KV = K2 @ V   (A: stream K2 panels; B: it==0 ? same K2 panel (V0^T = sc*K2) : BB=V^T)
    {
      f4v acc[4][4] = {};
#pragma unroll 1
      for (int kc = 0; kc < 4; ++kc) {
        __syncthreads();
        gload16(K2h + kbase + pr * 128 + kc * 32 + pc, (char*)SA + w * 1024);
        gload16(K2h + kbase + (64 + pr) * 128 + kc * 32 + pc, (char*)SA + 4096 + w * 1024);
        gload16(K2l + kbase + pr * 128 + kc * 32 + pc, (char*)SA + 8192 + w * 1024);
        gload16(K2l + kbase + (64 + pr) * 128 + kc * 32 + pc, (char*)SA + 12288 + w * 1024);
        __syncthreads();
        s8v ah[4], al[4], bhv[4], blv[4];
#pragma unroll
        for (int mi = 0; mi < 4; ++mi) {
          ah[mi] = *(s8v*)&SA[(wr + mi * 16 + c16) * 32 + 8 * g];
          al[mi] = *(s8v*)&SA[4096 + (wr + mi * 16 + c16) * 32 + 8 * g];
        }
        if (it == 0) {
#pragma unroll
          for (int ni = 0; ni < 4; ++ni) {
            bhv[ni] = *(s8v*)&SA[(wc + ni * 16 + c16) * 32 + 8 * g];
            blv[ni] = *(s8v*)&SA[4096 + (wc + ni * 16 + c16) * 32 + 8 * g];
          }
        } else {
#pragma unroll
          for (int ni = 0; ni < 4; ++ni) {
            bhv[ni] = *(s8v*)&BB[0][wc + ni * 16 + c16][kc * 32 + 8 * g];
            blv[ni] = *(s8v*)&BB[1][wc + ni * 16 + c16][kc * 32 + 8 * g];
          }
        }
#pragma unroll
        for (int mi = 0; mi < 4; ++mi)
#pragma unroll
          for (int ni = 0; ni < 4; ++ni) {
            acc[mi][ni] = MFMA(ah[mi], bhv[ni], acc[mi][ni]);
            acc[mi][ni] = MFMA(ah[mi], blv[ni], acc[mi][ni]);
            acc[mi][ni] = MFMA(al[mi], bhv[ni], acc[mi][ni]);
          }
      }
      __syncthreads();
      // write KV rows -> BA ; U1^T = 7I - KV^T -> BB
#pragma unroll
      for (int mi = 0; mi < 4; ++mi)
#pragma unroll
        for (int ni = 0; ni < 4; ++ni) {
          const int rb = wr + mi * 16 + 4 * g;
          const int cc = wc + ni * 16 + c16;
          s4v th, tl;
#pragma unroll
          for (int r = 0; r < 4; ++r) {
            float v = acc[mi][ni][r];
            if (it == 0) v *= sc;
            const unsigned short hh = f2bf(v);
            BA[0][rb + r][cc] = hh;
            BA[1][rb + r][cc] = f2bf(v - bf2f(hh));
            const float tv = ((rb + r) == cc ? 7.0f : 0.0f) - v;
            const unsigned short thh = f2bf(tv);
            th[r] = (short)thh;
            tl[r] = (short)f2bf(tv - bf2f(thh));
          }
          *(s4v*)&BB[0][cc][rb] = th;
          *(s4v*)&BB[1][cc][rb] = tl;
        }
      __syncthreads();
    }
    // ---- P2: M2 = KV @ U1 ; BB <- U2^T = 15I - M2^T
    {
      f4v acc[4][4] = {};
#pragma unroll 1
      for (int kc = 0; kc < 4; ++kc) {
        s8v ah[4], al[4], bhv[4], blv[4];
#pragma unroll
        for (int mi = 0; mi < 4; ++mi) {
          ah[mi] = *(s8v*)&BA[0][wr + mi * 16 + c16][kc * 32 + 8 * g];
          al[mi] = *(s8v*)&BA[1][wr + mi * 16 + c16][kc * 32 + 8 * g];
        }
#pragma unroll
        for (int ni = 0; ni < 4; ++ni) {
          bhv[ni] = *(s8v*)&BB[0][wc + ni * 16 + c16][kc * 32 + 8 * g];
          blv[ni] = *(s8v*)&BB[1][wc + ni * 16 + c16][kc * 32 + 8 * g];
        }
#pragma unroll
        for (int mi = 0; mi < 4; ++mi)
#pragma unroll
          for (int ni = 0; ni < 4; ++ni) {
            acc[mi][ni] = MFMA(ah[mi], bhv[ni], acc[mi][ni]);
            acc[mi][ni] = MFMA(ah[mi], blv[ni], acc[mi][ni]);
            acc[mi][ni] = MFMA(al[mi], bhv[ni], acc[mi][ni]);
          }
      }
      __syncthreads();
#pragma unroll
      for (int mi = 0; mi < 4; ++mi)
#pragma unroll
        for (int ni = 0; ni < 4; ++ni) {
          const int rb = wr + mi * 16 + 4 * g;
          const int cc = wc + ni * 16 + c16;
          s4v th, tl;
#pragma unroll
          for (int r = 0; r < 4; ++r) {
            const float tv = ((rb + r) == cc ? 15.0f : 0.0f) - acc[mi][ni][r];
            const unsigned short thh = f2bf(tv);
            th[r] = (short)thh;
            tl[r] = (short)f2bf(tv - bf2f(thh));
          }
          *(s4v*)&BB[0][cc][rb] = th;
          *(s4v*)&BB[1][cc][rb] = tl;
        }
      __syncthreads();
    }
    // ---- P3: M3 = KV @ U2 ; BA <- U3^T = 13I - M3^T
    {
      f4v acc[4][4] = {};
#pragma unroll 1
      for (int kc = 0; kc < 4; ++kc) {
        s8v ah[4], al[4], bhv[4], blv[4];
#pragma unroll
        for (int mi = 0; mi < 4; ++mi) {
          ah[mi] = *(s8v*)&BA[0][wr + mi * 16 + c16][kc * 32 + 8 * g];
          al[mi] = *(s8v*)&BA[1][wr + mi * 16 + c16][kc * 32 + 8 * g];
        }
#pragma unroll
        for (int ni = 0; ni < 4; ++ni) {
          bhv[ni] = *(s8v*)&BB[0][wc + ni * 16 + c16][kc * 32 + 8 * g];
          blv[ni] = *(s8v*)&BB[1][wc + ni * 16 + c16][kc * 32 + 8 * g];
        }
#pragma unroll
        for (int mi = 0; mi < 4; ++mi)
#pragma unroll
          for (int ni = 0; ni < 4; ++ni) {
            acc[mi][ni] = MFMA(ah[mi], bhv[ni], acc[mi][ni]);
            acc[mi][ni] = MFMA(ah[mi], blv[ni], acc[mi][ni]);
            acc[mi][ni] = MFMA(al[mi], bhv[ni], acc[mi][ni]);
          }
      }
      __syncthreads();
#pragma unroll
      for (int mi = 0; mi < 4; ++mi)
#pragma unroll
        for (int ni = 0; ni < 4; ++ni) {
          const int rb = wr + mi * 16 + 4 * g;
          const int cc = wc + ni * 16 + c16;
          s4v th, tl;
#pragma unroll
          for (int r = 0; r < 4; ++r) {
            const float tv = ((rb + r) == cc ? 13.0f : 0.0f) - acc[mi][ni][r];
            const unsigned short thh = f2bf(tv);
            th[r] = (short)thh;
            tl[r] = (short)f2bf(tv - bf2f(thh));
          }
          *(s4v*)&BA[0][cc][rb] = th;
          *(s4v*)&BA[1][cc][rb] = tl;
        }
      __syncthreads();
    }
    // ---- P4: V' = 0.25 * V @ U3   (A: stream V panels; B: BA = U3^T)
    {
      f4v acc[4][4] = {};
#pragma unroll 1
      for (int kc = 0; kc < 4; ++kc) {
        __syncthreads();
        gload16(Vh + kbase + pr * 128 + kc * 32 + pc, (char*)SB + w * 1024);
        gload16(Vh + kbase + (64 + pr) * 128 + kc * 32 + pc, (char*)SB + 4096 + w * 1024);
        gload16(Vl + kbase + pr * 128 + kc * 32 + pc, (char*)SB + 8192 + w * 1024);
        gload16(Vl + kbase + (64 + pr) * 128 + kc * 32 + pc, (char*)SB + 12288 + w * 1024);
        __syncthreads();
        s8v ah[4], al[4], bhv[4], blv[4];
#pragma unroll
        for (int mi = 0; mi < 4; ++mi) {
          ah[mi] = *(s8v*)&SB[(wr + mi * 16 + c16) * 32 + 8 * g];
          al[mi] = *(s8v*)&SB[4096 + (wr + mi * 16 + c16) * 32 + 8 * g];
        }
#pragma unroll
        for (int ni = 0; ni < 4; ++ni) {
          bhv[ni] = *(s8v*)&BA[0][wc + ni * 16 + c16][kc * 32 + 8 * g];
          blv[ni] = *(s8v*)&BA[1][wc + ni * 16 + c16][kc * 32 + 8 * g];
        }
#pragma unroll
        for (int mi = 0; mi < 4; ++mi)
#pragma unroll
          for (int ni = 0; ni < 4; ++ni) {
            acc[mi][ni] = MFMA(ah[mi], bhv[ni], acc[mi][ni]);
            acc[mi][ni] = MFMA(ah[mi], blv[ni], acc[mi][ni]);
            acc[mi][ni] = MFMA(al[mi], bhv[ni], acc[mi][ni]);
          }
      }
      __syncthreads();
#pragma unroll
      for (int mi = 0; mi < 4; ++mi)
#pragma unroll
        for (int ni = 0; ni < 4; ++ni) {
          const int rb = wr + mi * 16 + 4 * g;
          const int cc = wc + ni * 16 + c16;
          if (it < 5) {
            s4v th, tl;
#pragma unroll
            for (int r = 0; r < 4; ++r) {
              const float v = 0.25f * acc[mi][ni][r];
              const unsigned short hh = f2bf(v);
              const unsigned short ll = f2bf(v - bf2f(hh));
              Vh[kbase + (rb + r) * 128 + cc] = hh;  // V' rows -> global (A-src next iter)
              Vl[kbase + (rb + r) * 128 + cc] = ll;
              th[r] = (short)hh;
              tl[r] = (short)ll;
            }
            *(s4v*)&BB[0][cc][rb] = th;  // V'^T rows -> BB (B-src next P1)
            *(s4v*)&BB[1][cc][rb] = tl;
          } else {
#pragma unroll
            for (int r = 0; r < 4; ++r) {  // final: V rows -> BB (A-src for P5)
              const float v = 0.25f * acc[mi][ni][r];
              const unsigned short hh = f2bf(v);
              BB[0][rb + r][cc] = hh;
              BB[1][rb + r][cc] = f2bf(v - bf2f(hh));
            }
          }
        }
      __syncthreads();  // also drains global V' stores (vmcnt before barrier)
    }
  }
  // ---- P5: Z = Vfinal @ k3v  (A: BB rows; B: stream k3 = (k3v)^T rows)
  {
    f4v az[4][2] = {};
    const int wcz = (w & 1) * 32;
#pragma unroll 1
    for (int kc = 0; kc < 4; ++kc) {
      __syncthreads();
      gload16(k3h + (long)bh * 8192 + pr * 128 + kc * 32 + pc, (char*)SA + w * 1024);
      gload16(k3l + (long)bh * 8192 + pr * 128 + kc * 32 + pc, (char*)SA + 4096 + w * 1024);
      __syncthreads();
      s8v ah[4], al[4], bhv[2], blv[2];
#pragma unroll
      for (int mi = 0; mi < 4; ++mi) {
        ah[mi] = *(s8v*)&BB[0][wr + mi * 16 + c16][kc * 32 + 8 * g];
        al[mi] = *(s8v*)&BB[1][wr + mi * 16 + c16][kc * 32 + 8 * g];
      }
#pragma unroll
      for (int ni = 0; ni < 2; ++ni) {
        bhv[ni] = *(s8v*)&SA[(wcz + ni * 16 + c16) * 32 + 8 * g];
        blv[ni] = *(s8v*)&SA[2048 + (wcz + ni * 16 + c16) * 32 + 8 * g];
      }
#pragma unroll
      for (int mi = 0; mi < 4; ++mi)
#pragma unroll
        for (int ni = 0; ni < 2; ++ni) {
          az[mi][ni] = MFMA(ah[mi], bhv[ni], az[mi][ni]);
          az[mi][ni] = MFMA(ah[mi], blv[ni], az[mi][ni]);
          az[mi][ni] = MFMA(al[mi], bhv[ni], az[mi][ni]);
        }
    }
#pragma unroll
    for (int mi = 0; mi < 4; ++mi)
#pragma unroll
      for (int ni = 0; ni < 2; ++ni) {
        const int rb = wr + mi * 16 + 4 * g;
        const int cc = wcz + ni * 16 + c16;
        s4v th, tl;
#pragma unroll
        for (int r = 0; r < 4; ++r) {
          const float z = az[mi][ni][r];
          const unsigned short hh = f2bf(z);
          th[r] = (short)hh;
          tl[r] = (short)f2bf(z - bf2f(hh));
        }
        *(s4v*)&ZTh[((long)bh * 64 + cc) * 128 + rb] = th;
        *(s4v*)&ZTl[((long)bh * 64 + cc) * 128 + rb] = tl;
      }
  }
}

// ---------------------------------------------------------------- v^T materialization [bh][80][L] (row 64 = ones)
__global__ __launch_bounds__(256) void k_vt(const unsigned short* __restrict__ vb,
                                            unsigned short* __restrict__ vT) {
  __shared__ unsigned short T[64][72];
  const int lt = blockIdx.x, bh = blockIdx.y;
  const int b = bh >> 4, h = bh & 15;
  const int t = threadIdx.x;
  {
    const int r = t >> 2, c0 = (t & 3) * 16;
    const unsigned short* src = vb + ((b * 4096 + lt * 64 + r) * 16 + h) * 64 + c0;
    *(s8v*)&T[r][c0] = *(const s8v*)src;
    *(s8v*)&T[r][c0 + 8] = *(const s8v*)(src + 8);
  }
  __syncthreads();
  {
    const int d = t >> 2, c0 = (t & 3) * 16;
    unsigned short* dst = vT + ((long)bh * 80 + d) * 4096 + lt * 64 + c0;
    s8v o0, o1;
#pragma unroll
    for (int j = 0; j < 8; ++j) {
      o0[j] = (short)T[c0 + j][d];
      o1[j] = (short)T[c0 + 8 + j][d];
    }
    *(s8v*)dst = o0;
    *(s8v*)(dst + 8) = o1;
  }
  if (t < 64) vT[((long)bh * 80 + 64) * 4096 + lt * 64 + t] = 0x3F80;  // ones row
}

// ---------------------------------------------------------------- kernel_3 @ v, flash over L
__global__ __launch_bounds__(256) void k_flash(const unsigned short* __restrict__ Qlb,
                                               const unsigned short* __restrict__ kb,
                                               const unsigned short* __restrict__ vT,
                                               float* __restrict__ Opart,
                                               float* __restrict__ dpart) {
  __shared__ unsigned short P3[128 * 72];
  const int chunk = blockIdx.x, bh = blockIdx.y;
  const int b = bh >> 4, h = bh & 15;
  const int t = threadIdx.x, lane = t & 63, w = t >> 6;
  const int c16 = lane & 15, g = lane >> 4;
  s8v aq[8][2];
#pragma unroll
  for (int mi = 0; mi < 8; ++mi)
#pragma unroll
    for (int ks = 0; ks < 2; ++ks)
      aq[mi][ks] = *(const s8v*)&Qlb[(bh * 128 + mi * 16 + c16) * 64 + ks * 32 + 8 * g];
  f4v accO[2][5] = {};
  for (int s = 0; s < 16; ++s) {
    const int l0 = chunk * 1024 + s * 64;
    const int lcol = l0 + 16 * w + c16;
    const unsigned short* kr = &kb[((b * 4096 + lcol) * 16 + h) * 64];
    s8v bk0 = *(const s8v*)&kr[8 * g];
    s8v bk1 = *(const s8v*)&kr[32 + 8 * g];
    f4v p[8];
#pragma unroll
    for (int mi = 0; mi < 8; ++mi) {
      f4v a = {};
      a = MFMA(aq[mi][0], bk0, a);
      a = MFMA(aq[mi][1], bk1, a);
      p[mi] = a;
    }
    __syncthreads();
#pragma unroll
    for (int mi = 0; mi < 8; ++mi)
#pragma unroll
      for (int r = 0; r < 4; ++r)
        P3[(mi * 16 + 4 * g + r) * 72 + 16 * w + c16] = f2bf(__expf(p[mi][r]));
    __syncthreads();
#pragma unroll
    for (int ks = 0; ks < 2; ++ks) {
      s8v ap0 = *(s8v*)&P3[(32 * w + c16) * 72 + ks * 32 + 8 * g];
      s8v ap1 = *(s8v*)&P3[(32 * w + 16 + c16) * 72 + ks * 32 + 8 * g];
#pragma unroll
      for (int ni = 0; ni < 5; ++ni) {
        s8v bv = *(const s8v*)&vT[((long)bh * 80 + ni * 16 + c16) * 4096 + l0 + ks * 32 + 8 * g];
        accO[0][ni] = MFMA(ap0, bv, accO[0][ni]);
        accO[1][ni] = MFMA(ap1, bv, accO[1][ni]);
      }
    }
  }
  const long obase = ((long)bh * 4 + chunk) * 128 * 64;
#pragma unroll
  for (int mi2 = 0; mi2 < 2; ++mi2)
#pragma unroll
    for (int ni = 0; ni < 4; ++ni)
#pragma unroll
      for (int r = 0; r < 4; ++r)
        Opart[obase + (32 * w + mi2 * 16 + 4 * g + r) * 64 + ni * 16 + c16] = accO[mi2][ni][r];
  if (c16 == 0) {
#pragma unroll
    for (int mi2 = 0; mi2 < 2; ++mi2)
#pragma unroll
      for (int r = 0; r < 4; ++r)
        dpart[(bh * 4 + chunk) * 128 + 32 * w + mi2 * 16 + 4 * g + r] = accO[mi2][4][r];
  }
}

// ---------------------------------------------------------------- combine partials -> k3v^T hi/lo bf16 [bh][d][m]
__global__ __launch_bounds__(256) void k_comb(const float* __restrict__ Opart,
                                              const float* __restrict__ dpart,
                                              unsigned short* __restrict__ k3h,
                                              unsigned short* __restrict__ k3l) {
  const int bh = blockIdx.x;
  const int t = threadIdx.x;
  for (int idx = t; idx < 8192; idx += 256) {
    const int m = idx >> 6, d = idx & 63;
    float s = 0.f, den = 0.f;
#pragma unroll
    for (int c = 0; c < 4; ++c) {
      s += Opart[(((long)bh * 4 + c) * 128 + m) * 64 + d];
      den += dpart[(bh * 4 + c) * 128 + m];
    }
    const float v = s / den;
    const unsigned short hh = f2bf(v);
    k3h[((long)bh * 64 + d) * 128 + m] = hh;
    k3l[((long)bh * 64 + d) * 128 + m] = f2bf(v - bf2f(hh));
  }
}

// ---------------------------------------------------------------- kernel_1: softmax(q @ K_l^T) -> P1 bf16
__global__ __launch_bounds__(256) void k_p1(const unsigned short* __restrict__ qb,
                                            const unsigned short* __restrict__ Klb,
                                            unsigned short* __restrict__ P1) {
  const int lt = blockIdx.x, bh = blockIdx.y;
  const int b = bh >> 4, h = bh & 15;
  const int t = threadIdx.x, lane = t & 63, w = t >> 6;
  const int c16 = lane & 15, g = lane >> 4;
  const int lrow = lt * 64 + 16 * w + c16;
  const unsigned short* qr = &qb[((b * 4096 + lrow) * 16 + h) * 64];
  s8v aq0 = *(const s8v*)&qr[8 * g];
  s8v aq1 = *(const s8v*)&qr[32 + 8 * g];
  f4v acc[8];
#pragma unroll
  for (int ni = 0; ni < 8; ++ni) {
    f4v a = {};
    s8v b0 = *(const s8v*)&Klb[(bh * 128 + ni * 16 + c16) * 64 + 8 * g];
    s8v b1 = *(const s8v*)&Klb[(bh * 128 + ni * 16 + c16) * 64 + 32 + 8 * g];
    a = MFMA(aq0, b0, a);
    a = MFMA(aq1, b1, a);
    acc[ni] = a;
  }
#pragma unroll
  for (int r = 0; r < 4; ++r) {
    float mx = -1e30f;
#pragma unroll
    for (int ni = 0; ni < 8; ++ni) mx = fmaxf(mx, acc[ni][r]);
#pragma unroll
    for (int off = 1; off < 16; off <<= 1) mx = fmaxf(mx, __shfl_xor(mx, off));
    float sm = 0.f;
#pragma unroll
    for (int ni = 0; ni < 8; ++ni) {
      const float e = __expf(acc[ni][r] - mx);
      acc[ni][r] = e;
      sm += e;
    }
#pragma unroll
    for (int off = 1; off < 16; off <<= 1) sm += __shfl_xor(sm, off);
    const float is = 1.0f / sm;
    const int row = lt * 64 + 16 * w + 4 * g + r;
#pragma unroll
    for (int ni = 0; ni < 8; ++ni)
      P1[((long)bh * 4096 + row) * 128 + ni * 16 + c16] = f2bf(acc[ni][r] * is);
  }
}

// ---------------------------------------------------------------- X = P1 @ Z -> bf16 [B,L,1024]
__global__ __launch_bounds__(256) void k_xg(const unsigned short* __restrict__ P1,
                                            const unsigned short* __restrict__ ZTh,
                                            const unsigned short* __restrict__ ZTl,
                                            unsigned short* __restrict__ Xb) {
  const int lt = blockIdx.x, bh = blockIdx.y;
  const int b = bh >> 4, h = bh & 15;
  const int t = threadIdx.x, lane = t & 63, w = t >> 6;
  const int c16 = lane & 15, g = lane >> 4;
  const int wr = w * 32;
  f4v acc[2][4] = {};
  for (int kc = 0; kc < 4; ++kc) {
    s8v ap[2];
#pragma unroll
    for (int mi = 0; mi < 2; ++mi)
      ap[mi] = *(const s8v*)&P1[((long)bh * 4096 + lt * 128 + wr + mi * 16 + c16) * 128 + kc * 32 + 8 * g];
#pragma unroll
    for (int ni = 0; ni < 4; ++ni) {
      s8v zh = *(const s8v*)&ZTh[((long)bh * 64 + ni * 16 + c16) * 128 + kc * 32 + 8 * g];
      s8v zl = *(const s8v*)&ZTl[((long)bh * 64 + ni * 16 + c16) * 128 + kc * 32 + 8 * g];
#pragma unroll
      for (int mi = 0; mi < 2; ++mi) {
        acc[mi][ni] = MFMA(ap[mi], zh, acc[mi][ni]);
        acc[mi][ni] = MFMA(ap[mi], zl, acc[mi][ni]);
      }
    }
  }
#pragma unroll
  for (int mi = 0; mi < 2; ++mi)
#pragma unroll
    for (int ni = 0; ni < 4; ++ni)
#pragma unroll
      for (int r = 0; r < 4; ++r) {
        const int row = lt * 128 + wr + mi * 16 + 4 * g + r;
        Xb[((long)b * 4096 + row) * 1024 + h * 64 + ni * 16 + c16] = f2bf(acc[mi][ni][r]);
      }
}

// ================================================================ host
extern "C" void kernel_launch(void* const* d_in, const int* in_sizes, int n_in,
                              void* d_out, int out_size, void* d_ws, size_t ws_size,
                              hipStream_t stream) {
  (void)in_sizes; (void)n_in; (void)out_size;
  const float* queries = (const float*)d_in[0];
  const float* keys = (const float*)d_in[1];
  const float* values = (const float*)d_in[2];
  const float* Wq = (const float*)d_in[3];
  const float* bq = (const float*)d_in[4];
  const float* Wk = (const float*)d_in[5];
  const float* bk = (const float*)d_in[6];
  const float* Wv = (const float*)d_in[7];
  const float* bv = (const float*)d_in[8];
  const float* Wo = (const float*)d_in[9];
  const float* bo = (const float*)d_in[10];
  char* ws = (char*)d_ws;
  if (ws_size < (size_t)197263360) return;

  unsigned short* qb = (unsigned short*)(ws + 0);
  unsigned short* kb = (unsigned short*)(ws + 33554432);
  unsigned short* vb = (unsigned short*)(ws + 67108864);
  unsigned short* ti = (unsigned short*)(ws + 100663296);  // cvt scratch (pre-GEMM)
  float* Opart = (float*)(ws + 100663296);                 // reuse after GEMMs
  float* dpart = (float*)(ws + 109051904);
  unsigned short* WT = (unsigned short*)(ws + 134217728);
  unsigned short* vT = (unsigned short*)(ws + 136314880);  // 40MB, after GEMMs
  float* Qlf = (float*)(ws + 178257920);
  float* Klf = (float*)(ws + 180355072);
  unsigned short* Qlb = (unsigned short*)(ws + 182452224);
  unsigned short* Klb = (unsigned short*)(ws + 183500800);
  unsigned short* K2h = (unsigned short*)(ws + 184549376);
  unsigned short* K2l = (unsigned short*)(ws + 186646528);
  unsigned short* Vh = (unsigned short*)(ws + 188743680);
  unsigned short* Vl = (unsigned short*)(ws + 190840832);
  unsigned short* k3h = (unsigned short*)(ws + 192937984);
  unsigned short* k3l = (unsigned short*)(ws + 193986560);
  unsigned short* ZTh = (unsigned short*)(ws + 195035136);
  unsigned short* ZTl = (unsigned short*)(ws + 196083712);
  float* scale = (float*)(ws + 197132288);
  unsigned short* Xb = qb;                      // q dead after k_p1
  unsigned short* P1 = (unsigned short*)d_out;  // bf16 P1 scratch in d_out (exact fit)

  // projections (cvt scratch reused serially)
  k_wt<<<dim3(16, 16), 256, 0, stream>>>(Wq, WT);
  k_cvt<<<dim3(8192), 256, 0, stream>>>(queries, ti);
  k_gemm<false><<<dim3(1024), 256, 0, stream>>>(ti, WT, bq, qb);
  k_wt<<<dim3(16, 16), 256, 0, stream>>>(Wk, WT);
  k_cvt<<<dim3(8192), 256, 0, stream>>>(keys, ti);
  k_gemm<false><<<dim3(1024), 256, 0, stream>>>(ti, WT, bk, kb);
  k_wt<<<dim3(16, 16), 256, 0, stream>>>(Wv, WT);
  k_cvt<<<dim3(8192), 256, 0, stream>>>(values, ti);
  k_gemm<false><<<dim3(1024), 256, 0, stream>>>(ti, WT, bv, vb);
  // landmarks + kernel_2 softmax (fp32) + NS init
  k_land<<<dim3(32, 64, 2), 256, 0, stream>>>(qb, kb, Qlf, Klf, Qlb, Klb);
  k_k2<<<dim3(64), 256, 0, stream>>>(Qlf, Klf, K2h, K2l, Vh, Vl, scale);
  // kernel_3 @ v (flash over L)
  k_vt<<<dim3(64, 64), 256, 0, stream>>>(vb, vT);
  k_flash<<<dim3(4, 64), 256, 0, stream>>>(Qlb, kb, vT, Opart, dpart);
  k_comb<<<dim3(64), 256, 0, stream>>>(Opart, dpart, k3h, k3l);
  // fused Newton-Schulz (6 iters) + Z = inv @ k3v
  k_ns<<<dim3(64), 256, 0, stream>>>(K2h, K2l, Vh, Vl, k3h, k3l, scale, ZTh, ZTl);
  // kernel_1 softmax -> P1 (in d_out), X = P1 @ Z
  k_p1<<<dim3(64, 64), 256, 0, stream>>>(qb, Klb, P1);
  k_xg<<<dim3(32, 64), 256, 0, stream>>>(P1, ZTh, ZTl, Xb);
  // out = X @ Wo + bo
  k_wt<<<dim3(16, 16), 256, 0, stream>>>(Wo, WT);
  k_gemm<true><<<dim3(1024), 256, 0, stream>>>(Xb, WT, bo, (float*)d_out);
}